// Round 4
// baseline (1771.703 us; speedup 1.0000x reference)
//
#include <hip/hip_runtime.h>

// DeepAR forward: B=32, L_IN=336, L_OUT=48, N=512, COV=4, EMB=32, H=64
// T=383 steps, 16384 independent sequences.
// R4: 512-thread WGs (8 waves) = two independent 16-seq halves sharing one
// 64 KB layer-1 weight copy in LDS -> 4096 waves chip-wide (4/SIMD, 2x R3).
// Elementwise: 6 trans-ops/element (3 exp + 3 rcp; tanh via Pade(7,6) with
// rcp merged into the neighboring sigmoid's denominator). Trans pipe is the
// measured bottleneck (~4 lanes/cyc/SIMD).

#define T_STEPS 383
#define AST 168   // A row stride in shorts: [h0 0..63 | h1 64..127 | in 128..132 | pad]

typedef __attribute__((ext_vector_type(8))) short short8;
typedef __attribute__((ext_vector_type(4))) float floatx4;

__device__ __forceinline__ unsigned short f2bf(float f){   // RNE (prologue)
  union { float f; unsigned u; } v; v.f = f;
  unsigned u = v.u + 0x7fffu + ((v.u >> 16) & 1u);
  return (unsigned short)(u >> 16);
}
__device__ __forceinline__ unsigned short f2bf_fast(float f){  // round-half-up
  union { float f; unsigned u; } v; v.f = f;
  return (unsigned short)((v.u + 0x8000u) >> 16);
}
__device__ __forceinline__ float bf2f(unsigned short b){
  union { unsigned u; float f; } v; v.u = ((unsigned)b) << 16; return v.f;
}

__global__ __launch_bounds__(512, 4) void deepar_kernel(
    const float* __restrict__ hist, const float* __restrict__ fut,
    const float* __restrict__ embW, const float* __restrict__ embB,
    const float* __restrict__ Wih0, const float* __restrict__ Whh0,
    const float* __restrict__ bih0, const float* __restrict__ bhh0,
    const float* __restrict__ Wih1, const float* __restrict__ Whh1,
    const float* __restrict__ bih1, const float* __restrict__ bhh1,
    const float* __restrict__ headW, const float* __restrict__ headB,
    float* __restrict__ outp)
{
  const int tid  = threadIdx.x;
  const int lane = tid & 63;
  const int w    = tid >> 6;        // wave 0..7
  const int sub  = w & 3;           // hidden-unit sub-block (gate columns)
  const int hh   = w >> 2;          // sequence half (0: seqs 0-15, 1: 16-31)
  const int l15  = lane & 15;
  const int quad = lane >> 4;       // 0..3
  const int koff = quad * 8;
  const int jcol = sub * 16 + l15;  // hidden-unit index this lane owns

  const int b  = blockIdx.x >> 4;            // batch
  const int n0 = (blockIdx.x & 15) * 32;     // first series index

  __shared__ __align__(16) unsigned short A[32 * AST];
  __shared__ __align__(16) unsigned short W1[256 * 128];  // layer-1 B-frags (shared by both halves)
  __shared__ float HW[128];

  for (int i = tid; i < 32 * AST; i += 512) A[i] = 0;
  if (tid < 128) HW[tid] = headW[tid];
  const float hb0 = headB[0], hb1 = headB[1];

  // ---- layer-0 weight B-fragments in registers; layer-1 frags -> LDS ----
  // B-frag (16x16x32): lane holds B^T[n=lane&15][k = quad*8 + j], j=0..7
  short8 bf0[4][3];   // [gate][kf]: kf0,1 = Whh0 (k 0..63); kf2 = input cols
  float  bi0[4], bi1[4];
  #pragma unroll
  for (int g = 0; g < 4; ++g){
    const int r = g * 64 + sub * 16 + l15;    // gate row 0..255
    float u = 0.f, bb = bih0[r] + bhh0[r];
    #pragma unroll
    for (int e = 0; e < 32; ++e){
      float wval = Wih0[r * 36 + e];
      u  += wval * embW[e];
      bb += wval * embB[e];
    }
    bi0[g] = bb;
    bi1[g] = bih1[r] + bhh1[r];
    #pragma unroll
    for (int kf = 0; kf < 2; ++kf)
      #pragma unroll
      for (int j = 0; j < 8; ++j)
        bf0[g][kf][j] = (short)f2bf(Whh0[r * 64 + kf * 32 + koff + j]);
    #pragma unroll
    for (int j = 0; j < 8; ++j){
      int kk = koff + j;          // local k within input frag; col = 128+kk
      float v = 0.f;
      if (kk == 0) v = u;                               // prev -> u[r]
      else if (kk >= 1 && kk <= 4) v = Wih0[r * 36 + 32 + (kk - 1)];
      bf0[g][2][j] = (short)f2bf(v);
    }
    if (hh == 0){
      #pragma unroll
      for (int kf = 0; kf < 4; ++kf){
        const float* src = (kf < 2) ? (Wih1 + r * 64 + kf * 32)
                                    : (Whh1 + r * 64 + (kf - 2) * 32);
        short8 wv8;
        #pragma unroll
        for (int j = 0; j < 8; ++j)
          wv8[j] = (short)f2bf(src[koff + j]);
        *(short8*)&W1[(((sub * 16 + g * 4 + kf) * 64) + lane) * 8] = wv8;
      }
    }
  }

  // ---- input staging (prev: 32 threads; cov: 128 threads) ----
  const bool isPrev = (tid < 32);
  const bool isCov  = (tid >= 64 && tid < 192);
  int ss = 0, cc = 0;
  if (isPrev){ ss = tid; cc = 0; }
  if (isCov) { ss = (tid - 64) >> 2; cc = 1 + ((tid - 64) & 3); }
  const int myN = n0 + ss;

  auto loadSlab = [&](int tt) -> float {
    if (isPrev){
      int l = tt; if (l > 383) l = 383;
      return (l < 336) ? hist[(((size_t)b * 336 + l) * 512 + myN) * 5]
                       : fut [(((size_t)b * 48 + (l - 336)) * 512 + myN) * 5];
    } else if (isCov){
      int l = tt + 1; if (l > 383) l = 383;
      return (l < 336) ? hist[(((size_t)b * 336 + l) * 512 + myN) * 5 + cc]
                       : fut [(((size_t)b * 48 + (l - 336)) * 512 + myN) * 5 + cc];
    }
    return 0.f;
  };

  float rIn = loadSlab(0);
  if (isPrev || isCov) A[ss * AST + 128 + cc] = f2bf(rIn);
  rIn = loadSlab(1);   // prefetch step 1

  float c0s[4], c1s[4];
  #pragma unroll
  for (int i = 0; i < 4; ++i){ c0s[i] = 0.f; c1s[i] = 0.f; }

  __syncthreads();

  const int arow = (hh * 16 + l15) * AST;

  for (int t = 0; t < T_STEPS; ++t){
    // ================= layer 0 (K-frags at col 0,32,128) =================
    floatx4 acc[4];
    #pragma unroll
    for (int g = 0; g < 4; ++g){
      floatx4 binit = { bi0[g], bi0[g], bi0[g], bi0[g] };
      acc[g] = binit;
    }
    const int c0off[3] = { 0, 32, 128 };
    #pragma unroll
    for (int kf = 0; kf < 3; ++kf){
      short8 af = *(const short8*)&A[arow + c0off[kf] + koff];
      #pragma unroll
      for (int g = 0; g < 4; ++g)
        acc[g] = __builtin_amdgcn_mfma_f32_16x16x32_bf16(af, bf0[g][kf], acc[g], 0, 0, 0);
    }
    float hn[4];
    #pragma unroll
    for (int q = 0; q < 4; ++q){
      float iv = acc[0][q], fv = acc[1][q];
      float gv = acc[2][q], ov = acc[3][q];
      float ef = __expf(-fv), ei = __expf(-iv), eo = __expf(-ov);
      float gc = fmaxf(-4.97f, fminf(4.97f, gv));
      float g2 = gc * gc;
      float pg = gc * fmaf(g2, fmaf(g2, g2 + 378.f, 17325.f), 135135.f);
      float qg = fmaf(g2, fmaf(g2, fmaf(g2, 28.f, 3150.f), 62370.f), 135135.f);
      float c = c0s[q] * __builtin_amdgcn_rcpf(1.f + ef)
              + pg * __builtin_amdgcn_rcpf((1.f + ei) * qg);
      c0s[q] = c;
      float ct = fmaxf(-4.97f, fminf(4.97f, c));
      float c2 = ct * ct;
      float pc = ct * fmaf(c2, fmaf(c2, c2 + 378.f, 17325.f), 135135.f);
      float qc = fmaf(c2, fmaf(c2, fmaf(c2, 28.f, 3150.f), 62370.f), 135135.f);
      hn[q] = pc * __builtin_amdgcn_rcpf((1.f + eo) * qc);
    }
    __syncthreads();   // B1: all layer-0 reads of A done
    #pragma unroll
    for (int q = 0; q < 4; ++q){
      int s = hh * 16 + quad * 4 + q;
      A[s * AST + jcol] = f2bf_fast(hn[q]);   // h0(t)
    }
    if (isPrev || isCov) A[ss * AST + 128 + cc] = f2bf_fast(rIn);  // inputs t+1
    rIn = loadSlab(t + 2);                                          // prefetch t+2
    __syncthreads();   // B2: h0 + inputs visible

    // ================= layer 1 (K = h0|h1, cols 0..127; W from LDS) ======
    #pragma unroll
    for (int g = 0; g < 4; ++g){
      floatx4 binit = { bi1[g], bi1[g], bi1[g], bi1[g] };
      acc[g] = binit;
    }
    #pragma unroll
    for (int kf = 0; kf < 4; ++kf){
      short8 af = *(const short8*)&A[arow + kf * 32 + koff];
      #pragma unroll
      for (int g = 0; g < 4; ++g){
        short8 wfr = *(const short8*)&W1[(((sub * 16 + g * 4 + kf) * 64) + lane) * 8];
        acc[g] = __builtin_amdgcn_mfma_f32_16x16x32_bf16(af, wfr, acc[g], 0, 0, 0);
      }
    }
    #pragma unroll
    for (int q = 0; q < 4; ++q){
      float iv = acc[0][q], fv = acc[1][q];
      float gv = acc[2][q], ov = acc[3][q];
      float ef = __expf(-fv), ei = __expf(-iv), eo = __expf(-ov);
      float gc = fmaxf(-4.97f, fminf(4.97f, gv));
      float g2 = gc * gc;
      float pg = gc * fmaf(g2, fmaf(g2, g2 + 378.f, 17325.f), 135135.f);
      float qg = fmaf(g2, fmaf(g2, fmaf(g2, 28.f, 3150.f), 62370.f), 135135.f);
      float c = c1s[q] * __builtin_amdgcn_rcpf(1.f + ef)
              + pg * __builtin_amdgcn_rcpf((1.f + ei) * qg);
      c1s[q] = c;
      float ct = fmaxf(-4.97f, fminf(4.97f, c));
      float c2 = ct * ct;
      float pc = ct * fmaf(c2, fmaf(c2, c2 + 378.f, 17325.f), 135135.f);
      float qc = fmaf(c2, fmaf(c2, fmaf(c2, 28.f, 3150.f), 62370.f), 135135.f);
      hn[q] = pc * __builtin_amdgcn_rcpf((1.f + eo) * qc);
    }
    __syncthreads();   // B3: all layer-1 reads of h1(t-1) done
    #pragma unroll
    for (int q = 0; q < 4; ++q){
      int s = hh * 16 + quad * 4 + q;
      A[s * AST + 64 + jcol] = f2bf_fast(hn[q]);   // h1(t)
    }
    // next step's layer-0 reads only cols 0..63/128..; h1 readers are behind
    // B1+B2 of next step -> no barrier needed here except for the head.

    // ================= head (only last 48 steps produce output) =========
    if (t >= 335){
      __syncthreads();   // h1 visible for head reads
      const int hs = tid >> 4, outc = (tid >> 3) & 1, part = tid & 7;
      const short8 hv = *(const short8*)&A[hs * AST + 64 + part * 8];
      float p = 0.f;
      #pragma unroll
      for (int jj = 0; jj < 8; ++jj){
        float a0 = fmaxf(bf2f((unsigned short)hv[jj]), 0.f);
        p += a0 * HW[outc * 64 + part * 8 + jj];
      }
      p += __shfl_xor(p, 1);
      p += __shfl_xor(p, 2);
      p += __shfl_xor(p, 4);
      if (part == 0){
        float val;
        if (outc == 0) val = p + hb0;
        else {
          float x = p + hb1;   // softplus, stable
          val = fmaxf(x, 0.f) + __logf(1.f + __expf(-fabsf(x)));
        }
        outp[(((size_t)b * 48 + (t - 335)) * 512 + (n0 + hs)) * 2 + outc] = val;
      }
    }
  }
}

extern "C" void kernel_launch(void* const* d_in, const int* in_sizes, int n_in,
                              void* d_out, int out_size, void* d_ws, size_t ws_size,
                              hipStream_t stream) {
  (void)in_sizes; (void)n_in; (void)out_size; (void)d_ws; (void)ws_size;
  deepar_kernel<<<dim3(512), dim3(512), 0, stream>>>(
      (const float*)d_in[0],  (const float*)d_in[1],
      (const float*)d_in[2],  (const float*)d_in[3],
      (const float*)d_in[4],  (const float*)d_in[5],
      (const float*)d_in[6],  (const float*)d_in[7],
      (const float*)d_in[8],  (const float*)d_in[9],
      (const float*)d_in[10], (const float*)d_in[11],
      (const float*)d_in[12], (const float*)d_in[13],
      (float*)d_out);
}

// Round 5
// 1498.833 us; speedup vs baseline: 1.1821x; 1.1821x over previous
//
#include <hip/hip_runtime.h>

// DeepAR forward: B=32, L_IN=336, L_OUT=48, N=512, COV=4, EMB=32, H=64
// T=383 steps, 16384 independent sequences.
// R5: 512 WGs x 512 threads (8 waves = two 16-seq halves sharing one LDS
// copy of the layer-1 weights). launch_bounds(512,4) -> 128 regs/wave total,
// budgeted as AGPR: bf0(48)+acc(16)=64, VGPR: ~45 live. 4 waves/SIMD.
// Weights pre-scaled so gates use exp2 directly (i,f,o rows * -log2e,
// g rows * 2*log2e); merged-rcp activations: 8 trans + ~15 arith per elem.
// LDS: W1 64KB + H0[2][32][88] (h0|inputs, double-buffered, bank-free
// stride) + H1[32][72] (h1; row padding holds the head weights as floats).
// 2 barriers/step (+1 during the 48 output steps).

#define T_STEPS 383
#define LOG2E 1.4426950408889634f
#define K2    2.8853900817779268f   // 2*log2e

typedef __attribute__((ext_vector_type(8))) short short8;
typedef __attribute__((ext_vector_type(4))) float floatx4;

static __device__ __forceinline__ unsigned short f2bf(float f){   // RNE
  union { float f; unsigned u; } v; v.f = f;
  unsigned u = v.u + 0x7fffu + ((v.u >> 16) & 1u);
  return (unsigned short)(u >> 16);
}
static __device__ __forceinline__ unsigned short f2bf_fast(float f){
  union { float f; unsigned u; } v; v.f = f;
  return (unsigned short)((v.u + 0x8000u) >> 16);
}
static __device__ __forceinline__ float bf2f(unsigned short b){
  union { unsigned u; float f; } v; v.u = ((unsigned)b) << 16; return v.f;
}

// gates pre-scaled: iv=-i*log2e, fv=-f*log2e, gv=2g*log2e, ov=-o*log2e
static __device__ __forceinline__ float lstm_elem(float iv, float fv,
                                                  float gv, float ov,
                                                  float& c){
  float Ei = __builtin_amdgcn_exp2f(iv);
  float Ef = __builtin_amdgcn_exp2f(fv);
  float Eo = __builtin_amdgcn_exp2f(ov);
  float Eg = __builtin_amdgcn_exp2f(fminf(gv, 126.f));
  float rf = __builtin_amdgcn_rcpf(1.f + Ef);                 // sig(f)
  float r1 = __builtin_amdgcn_rcpf((Eg + 1.f) * (1.f + Ei));
  c = fmaf(c, rf, (Eg - 1.f) * r1);                           // sig(f)c + sig(i)tanh(g)
  float Ec = __builtin_amdgcn_exp2f(fminf(c * K2, 126.f));
  float r2 = __builtin_amdgcn_rcpf((Ec + 1.f) * (1.f + Eo));
  return (Ec - 1.f) * r2;                                     // sig(o)tanh(c)
}

__global__ __launch_bounds__(512, 4) void deepar_kernel(
    const float* __restrict__ hist, const float* __restrict__ fut,
    const float* __restrict__ embW, const float* __restrict__ embB,
    const float* __restrict__ Wih0, const float* __restrict__ Whh0,
    const float* __restrict__ bih0, const float* __restrict__ bhh0,
    const float* __restrict__ Wih1, const float* __restrict__ Whh1,
    const float* __restrict__ bih1, const float* __restrict__ bhh1,
    const float* __restrict__ headW, const float* __restrict__ headB,
    float* __restrict__ outp)
{
  const int tid  = threadIdx.x;
  const int lane = tid & 63;
  const int w    = tid >> 6;        // wave 0..7
  const int sub  = w & 3;           // gate-column sub-block
  const int hh   = w >> 2;          // sequence half
  const int l15  = lane & 15;
  const int quad = lane >> 4;
  const int koff = quad * 8;
  const int jcol = sub * 16 + l15;  // hidden-unit col this lane owns

  const int b  = blockIdx.x >> 4;
  const int n0 = (blockIdx.x & 15) * 32;

  // H0[buf][row][88]: cols 0..63 h0 | 64..68 inputs | 69..87 zero pad.
  // stride 88 shorts = 44 dwords == 12 mod 32 -> 16-row reads hit 8 distinct
  // 4-bank spans x2 lanes: conflict-free b128 reads.
  __shared__ __align__(16) short H0[2][32][88];
  __shared__ __align__(16) short H1[32][72];   // cols 0..63 h1 | 64..71: headW as 4 floats/row
  __shared__ __align__(16) short W1s[64 * 512]; // 64 frags x (64 lanes x 8 shorts)

  for (int i = tid; i < 2 * 32 * 88; i += 512) ((short*)H0)[i] = 0;
  for (int i = tid; i < 32 * 64; i += 512) H1[i >> 6][i & 63] = 0;
  if (tid < 32){
    floatx4 hw = { headW[4*tid], headW[4*tid+1], headW[4*tid+2], headW[4*tid+3] };
    *(floatx4*)&H1[tid][64] = hw;
  }
  const float hb0 = headB[0], hb1 = headB[1];

  // ---- weights: layer0 B-frags in registers (target: AGPRs), layer1 -> LDS
  // B-frag (16x16x32): lane holds B^T[n=l15][k=koff+j]
  short8 bf0[4][3];
  float  bi0[4], bi1[4];
  #pragma unroll
  for (int g = 0; g < 4; ++g){
    const float scale = (g == 2) ? K2 : -LOG2E;
    const int r = g * 64 + sub * 16 + l15;
    float u = 0.f, bb = bih0[r] + bhh0[r];
    #pragma unroll
    for (int e = 0; e < 32; ++e){
      float wval = Wih0[r * 36 + e];
      u  += wval * embW[e];
      bb += wval * embB[e];
    }
    bi0[g] = bb * scale;
    bi1[g] = (bih1[r] + bhh1[r]) * scale;
    #pragma unroll
    for (int kf = 0; kf < 2; ++kf)
      #pragma unroll
      for (int j = 0; j < 8; ++j)
        bf0[g][kf][j] = (short)f2bf(Whh0[r * 64 + kf * 32 + koff + j] * scale);
    #pragma unroll
    for (int j = 0; j < 8; ++j){
      int kk = koff + j;                 // input col = 64+kk in H0 row
      float v = 0.f;
      if (kk == 0) v = u;
      else if (kk >= 1 && kk <= 4) v = Wih0[r * 36 + 32 + (kk - 1)];
      bf0[g][2][j] = (short)f2bf(v * scale);
    }
    if (hh == 0){
      #pragma unroll
      for (int kf = 0; kf < 4; ++kf){
        const float* src = (kf < 2) ? (Wih1 + r * 64 + kf * 32)
                                    : (Whh1 + r * 64 + (kf - 2) * 32);
        short8 wv8;
        #pragma unroll
        for (int j = 0; j < 8; ++j)
          wv8[j] = (short)f2bf(src[koff + j] * scale);
        *(short8*)&W1s[((sub * 16 + g * 4 + kf) * 64 + lane) * 8] = wv8;
      }
    }
  }

  // ---- input staging (prev: threads 0..31; cov: threads 64..191) ----
  const bool isPrev = (tid < 32);
  const bool isCov  = (tid >= 64 && tid < 192);
  int ss = 0, cc = 0;
  if (isPrev){ ss = tid; cc = 0; }
  if (isCov) { ss = (tid - 64) >> 2; cc = 1 + ((tid - 64) & 3); }
  const int myN = n0 + ss;

  auto loadSlab = [&](int tt) -> float {
    if (isPrev){
      int l = tt; if (l > 383) l = 383;
      return (l < 336) ? hist[(((size_t)b * 336 + l) * 512 + myN) * 5]
                       : fut [(((size_t)b * 48 + (l - 336)) * 512 + myN) * 5];
    } else if (isCov){
      int l = tt + 1; if (l > 383) l = 383;
      return (l < 336) ? hist[(((size_t)b * 336 + l) * 512 + myN) * 5 + cc]
                       : fut [(((size_t)b * 48 + (l - 336)) * 512 + myN) * 5 + cc];
    }
    return 0.f;
  };

  __syncthreads();   // zero-init done before in(0) store

  // L0(t) reads h0(t-1)+in(t) from H0[(t+1)&1]; t=0 -> H0[1]
  if (isPrev || isCov) H0[1][ss][64 + cc] = f2bf(loadSlab(0));
  float rIn = loadSlab(1);   // in(1), stored into H0[0] during step 0

  float c0s[4], c1s[4];
  #pragma unroll
  for (int i = 0; i < 4; ++i){ c0s[i] = 0.f; c1s[i] = 0.f; }

  const int r88 = (hh * 16 + l15) * 88;
  const int r72 = (hh * 16 + l15) * 72;

  __syncthreads();

  for (int t = 0; t < T_STEPS; ++t){
    short* pA = &H0[(t + 1) & 1][0][0];   // h0(t-1) | in(t)
    short* cA = &H0[t & 1][0][0];         // h0(t)   | in(t+1)

    // ================= layer 0 =================
    floatx4 a0 = { bi0[0], bi0[0], bi0[0], bi0[0] };
    floatx4 a1 = { bi0[1], bi0[1], bi0[1], bi0[1] };
    floatx4 a2 = { bi0[2], bi0[2], bi0[2], bi0[2] };
    floatx4 a3 = { bi0[3], bi0[3], bi0[3], bi0[3] };
    #pragma unroll
    for (int kf = 0; kf < 2; ++kf){
      short8 af = *(const short8*)&pA[r88 + kf * 32 + koff];
      a0 = __builtin_amdgcn_mfma_f32_16x16x32_bf16(af, bf0[0][kf], a0, 0, 0, 0);
      a1 = __builtin_amdgcn_mfma_f32_16x16x32_bf16(af, bf0[1][kf], a1, 0, 0, 0);
      a2 = __builtin_amdgcn_mfma_f32_16x16x32_bf16(af, bf0[2][kf], a2, 0, 0, 0);
      a3 = __builtin_amdgcn_mfma_f32_16x16x32_bf16(af, bf0[3][kf], a3, 0, 0, 0);
    }
    {
      short8 afin = { 0,0,0,0,0,0,0,0 };
      if (quad == 0) afin = *(const short8*)&pA[r88 + 64];
      a0 = __builtin_amdgcn_mfma_f32_16x16x32_bf16(afin, bf0[0][2], a0, 0, 0, 0);
      a1 = __builtin_amdgcn_mfma_f32_16x16x32_bf16(afin, bf0[1][2], a1, 0, 0, 0);
      a2 = __builtin_amdgcn_mfma_f32_16x16x32_bf16(afin, bf0[2][2], a2, 0, 0, 0);
      a3 = __builtin_amdgcn_mfma_f32_16x16x32_bf16(afin, bf0[3][2], a3, 0, 0, 0);
    }
    #pragma unroll
    for (int q = 0; q < 4; ++q){
      float h = lstm_elem(a0[q], a1[q], a2[q], a3[q], c0s[q]);
      // h0(t) store: cA was last read two barriers ago (safe WAR)
      cA[(hh * 16 + quad * 4 + q) * 88 + jcol] = (short)f2bf_fast(h);
    }
    if (isPrev || isCov) cA[ss * 88 + 64 + cc] = (short)f2bf_fast(rIn); // in(t+1)
    rIn = loadSlab(t + 2);
    __syncthreads();   // B2: h0(t) + in(t+1) visible

    // ================= layer 1 (K = h0(t) | h1(t-1)) =================
    a0 = floatx4{ bi1[0], bi1[0], bi1[0], bi1[0] };
    a1 = floatx4{ bi1[1], bi1[1], bi1[1], bi1[1] };
    a2 = floatx4{ bi1[2], bi1[2], bi1[2], bi1[2] };
    a3 = floatx4{ bi1[3], bi1[3], bi1[3], bi1[3] };
    #pragma unroll
    for (int kf = 0; kf < 4; ++kf){
      short8 af = (kf < 2) ? *(const short8*)&cA[r88 + kf * 32 + koff]
                           : *(const short8*)&H1[0][r72 + (kf - 2) * 32 + koff];
      const int fbase = (sub * 16 + kf) * 64 * 8 + lane * 8;
      a0 = __builtin_amdgcn_mfma_f32_16x16x32_bf16(af, *(const short8*)&W1s[fbase        ], a0, 0, 0, 0);
      a1 = __builtin_amdgcn_mfma_f32_16x16x32_bf16(af, *(const short8*)&W1s[fbase + 4*512], a1, 0, 0, 0);
      a2 = __builtin_amdgcn_mfma_f32_16x16x32_bf16(af, *(const short8*)&W1s[fbase + 8*512], a2, 0, 0, 0);
      a3 = __builtin_amdgcn_mfma_f32_16x16x32_bf16(af, *(const short8*)&W1s[fbase +12*512], a3, 0, 0, 0);
    }
    float hn[4];
    #pragma unroll
    for (int q = 0; q < 4; ++q)
      hn[q] = lstm_elem(a0[q], a1[q], a2[q], a3[q], c1s[q]);
    __syncthreads();   // B3: all layer-1 reads of h1(t-1) done
    #pragma unroll
    for (int q = 0; q < 4; ++q)
      H1[hh * 16 + quad * 4 + q][jcol] = (short)f2bf_fast(hn[q]);

    // ================= head (last 48 steps only) =================
    if (t >= 335){
      __syncthreads();   // h1(t) visible
      const int hs = tid >> 4, outc = (tid >> 3) & 1, part = tid & 7;
      const int idx0 = outc * 64 + part * 8;
      short8 hv = *(const short8*)&H1[hs][part * 8];
      floatx4 wa = *(const floatx4*)&H1[idx0 >> 2][64];
      floatx4 wb = *(const floatx4*)&H1[(idx0 >> 2) + 1][64];
      float p = 0.f;
      #pragma unroll
      for (int jj = 0; jj < 4; ++jj){
        p += fmaxf(bf2f((unsigned short)hv[jj]), 0.f) * wa[jj];
        p += fmaxf(bf2f((unsigned short)hv[jj + 4]), 0.f) * wb[jj];
      }
      p += __shfl_xor(p, 1);
      p += __shfl_xor(p, 2);
      p += __shfl_xor(p, 4);
      if (part == 0){
        float val;
        if (outc == 0) val = p + hb0;
        else {
          float x = p + hb1;   // softplus, stable
          val = fmaxf(x, 0.f) + __logf(1.f + __expf(-fabsf(x)));
        }
        outp[(((size_t)b * 48 + (t - 335)) * 512 + (n0 + hs)) * 2 + outc] = val;
      }
    }
  }
}

extern "C" void kernel_launch(void* const* d_in, const int* in_sizes, int n_in,
                              void* d_out, int out_size, void* d_ws, size_t ws_size,
                              hipStream_t stream) {
  (void)in_sizes; (void)n_in; (void)out_size; (void)d_ws; (void)ws_size;
  deepar_kernel<<<dim3(512), dim3(512), 0, stream>>>(
      (const float*)d_in[0],  (const float*)d_in[1],
      (const float*)d_in[2],  (const float*)d_in[3],
      (const float*)d_in[4],  (const float*)d_in[5],
      (const float*)d_in[6],  (const float*)d_in[7],
      (const float*)d_in[8],  (const float*)d_in[9],
      (const float*)d_in[10], (const float*)d_in[11],
      (const float*)d_in[12], (const float*)d_in[13],
      (float*)d_out);
}

// Round 6
// 1470.061 us; speedup vs baseline: 1.2052x; 1.0196x over previous
//
#include <hip/hip_runtime.h>

// DeepAR forward: B=32, L_IN=336, L_OUT=48, N=512, COV=4, EMB=32, H=64
// T=383 steps, 16384 independent sequences.
// R6: 512 WGs x 512 threads, launch_bounds(512,4) -> 64V+64A per wave,
// 2 WGs/CU = 4 waves/SIMD. AGPR side: bf0 weights (48) + acc (16) = 64.
// VGPR side kept <=64 by (a) sched_barrier(0) per layer-1 kf group to stop
// the compiler hoisting all 16 W1 ds_read_b128s (~80 VGPRs of staging -> R5
// spilled), (b) scalar-uniform input staging (SGPR base + 1 VGPR offset).
// Gates pre-scaled for exp2 (i,f,o rows * -log2e; g rows * 2*log2e);
// merged-rcp activations: 8 trans + ~15 arith per element.
// LDS 81408B: W1 64KB + H0[2][32][88] (h0|inputs dbuf) + H1[32][72]
// (h1 | headW in row padding). 2 barriers/step (+1 in the 48 output steps).

#define T_STEPS 383
#define LOG2E 1.4426950408889634f
#define K2    2.8853900817779268f   // 2*log2e

typedef __attribute__((ext_vector_type(8))) short short8;
typedef __attribute__((ext_vector_type(4))) float floatx4;

static __device__ __forceinline__ unsigned short f2bf(float f){   // RNE
  union { float f; unsigned u; } v; v.f = f;
  unsigned u = v.u + 0x7fffu + ((v.u >> 16) & 1u);
  return (unsigned short)(u >> 16);
}
static __device__ __forceinline__ unsigned short f2bf_fast(float f){
  union { float f; unsigned u; } v; v.f = f;
  return (unsigned short)((v.u + 0x8000u) >> 16);
}
static __device__ __forceinline__ float bf2f(unsigned short b){
  union { unsigned u; float f; } v; v.u = ((unsigned)b) << 16; return v.f;
}

// gates pre-scaled: iv=-i*log2e, fv=-f*log2e, gv=2g*log2e, ov=-o*log2e
static __device__ __forceinline__ float lstm_elem(float iv, float fv,
                                                  float gv, float ov,
                                                  float& c){
  float Ei = __builtin_amdgcn_exp2f(iv);
  float Ef = __builtin_amdgcn_exp2f(fv);
  float Eo = __builtin_amdgcn_exp2f(ov);
  float Eg = __builtin_amdgcn_exp2f(fminf(gv, 126.f));
  float rf = __builtin_amdgcn_rcpf(1.f + Ef);                 // sig(f)
  float r1 = __builtin_amdgcn_rcpf((Eg + 1.f) * (1.f + Ei));
  c = fmaf(c, rf, (Eg - 1.f) * r1);                           // sig(f)c + sig(i)tanh(g)
  float Ec = __builtin_amdgcn_exp2f(fminf(c * K2, 126.f));
  float r2 = __builtin_amdgcn_rcpf((Ec + 1.f) * (1.f + Eo));
  return (Ec - 1.f) * r2;                                     // sig(o)tanh(c)
}

__global__ __launch_bounds__(512, 4) void deepar_kernel(
    const float* __restrict__ hist, const float* __restrict__ fut,
    const float* __restrict__ embW, const float* __restrict__ embB,
    const float* __restrict__ Wih0, const float* __restrict__ Whh0,
    const float* __restrict__ bih0, const float* __restrict__ bhh0,
    const float* __restrict__ Wih1, const float* __restrict__ Whh1,
    const float* __restrict__ bih1, const float* __restrict__ bhh1,
    const float* __restrict__ headW, const float* __restrict__ headB,
    float* __restrict__ outp)
{
  const int tid  = threadIdx.x;
  const int lane = tid & 63;
  const int w    = tid >> 6;        // wave 0..7
  const int sub  = w & 3;           // gate-column sub-block
  const int hh   = w >> 2;          // sequence half
  const int l15  = lane & 15;
  const int quad = lane >> 4;
  const int koff = quad * 8;
  const int jcol = sub * 16 + l15;  // hidden-unit col this lane owns

  const int b  = blockIdx.x >> 4;
  const int n0 = (blockIdx.x & 15) * 32;

  __shared__ __align__(16) short H0[2][32][88];  // h0 0..63 | in 64..68 | pad
  __shared__ __align__(16) short H1[32][72];     // h1 0..63 | headW 4 floats/row
  __shared__ __align__(16) short W1s[64 * 512];  // 64 frags x (64 lanes x 8 shorts)

  for (int i = tid; i < 2 * 32 * 88; i += 512) ((short*)H0)[i] = 0;
  for (int i = tid; i < 32 * 64; i += 512) H1[i >> 6][i & 63] = 0;
  if (tid < 32){
    floatx4 hw = { headW[4*tid], headW[4*tid+1], headW[4*tid+2], headW[4*tid+3] };
    *(floatx4*)&H1[tid][64] = hw;
  }
  const float hb0 = headB[0], hb1 = headB[1];

  // ---- weights: layer0 B-frags in registers (AGPR side), layer1 -> LDS ----
  // B-frag (16x16x32): lane holds B^T[n=l15][k=koff+j]
  short8 bf0[4][3];
  float  bi0[4], bi1[4];
  #pragma unroll
  for (int g = 0; g < 4; ++g){
    const float scale = (g == 2) ? K2 : -LOG2E;
    const int r = g * 64 + sub * 16 + l15;
    float u = 0.f, bb = bih0[r] + bhh0[r];
    #pragma unroll
    for (int e = 0; e < 32; ++e){
      float wval = Wih0[r * 36 + e];
      u  += wval * embW[e];
      bb += wval * embB[e];
    }
    bi0[g] = bb * scale;
    bi1[g] = (bih1[r] + bhh1[r]) * scale;
    #pragma unroll
    for (int kf = 0; kf < 2; ++kf)
      #pragma unroll
      for (int j = 0; j < 8; ++j)
        bf0[g][kf][j] = (short)f2bf(Whh0[r * 64 + kf * 32 + koff + j] * scale);
    #pragma unroll
    for (int j = 0; j < 8; ++j){
      int kk = koff + j;                 // input col = 64+kk in H0 row
      float v = 0.f;
      if (kk == 0) v = u;
      else if (kk >= 1 && kk <= 4) v = Wih0[r * 36 + 32 + (kk - 1)];
      bf0[g][2][j] = (short)f2bf(v * scale);
    }
    if (hh == 0){
      #pragma unroll
      for (int kf = 0; kf < 4; ++kf){
        const float* src = (kf < 2) ? (Wih1 + r * 64 + kf * 32)
                                    : (Whh1 + r * 64 + (kf - 2) * 32);
        short8 wv8;
        #pragma unroll
        for (int j = 0; j < 8; ++j)
          wv8[j] = (short)f2bf(src[koff + j] * scale);
        *(short8*)&W1s[((sub * 16 + g * 4 + kf) * 64 + lane) * 8] = wv8;
      }
    }
  }

  // ---- input staging: prev tid 0..31 (col 64), cov tid 64..191 (col 65..68)
  // Time index is wave-uniform -> scalar base select; per-thread part is a
  // single element offset (1 VGPR).
  const bool isPrev = (tid < 32);
  const bool isCov  = (tid >= 64 && tid < 192);
  const bool act    = isPrev || isCov;
  int ss = 0, cc = 0;
  if (isPrev){ ss = tid; cc = 0; }
  if (isCov) { ss = (tid - 64) >> 2; cc = 1 + ((tid - 64) & 3); }
  const int voff = (n0 + ss) * 5 + cc;           // element offset within a time slab
  const int tadj = isPrev ? 0 : 1;               // cov uses t+1
  const float* histB = hist + (size_t)b * 336 * 2560;
  const float* futB  = fut  + (size_t)b * 48 * 2560;

  auto loadSlab = [&](int tt) -> float {
    int l = tt + tadj; if (l > 383) l = 383;     // tadj divergent only prev/cov groups
    const float* p = (l < 336) ? histB + (size_t)l * 2560
                               : futB + (size_t)(l - 336) * 2560;
    return act ? p[voff] : 0.f;
  };

  __syncthreads();   // zero-init done before in(0) store

  // L0(t) reads h0(t-1)+in(t) from H0[(t+1)&1]; t=0 -> H0[1]
  if (act) H0[1][ss][64 + cc] = f2bf(loadSlab(0));
  float rIn = loadSlab(1);   // in(1), stored into H0[0] during step 0

  float c0s[4], c1s[4];
  #pragma unroll
  for (int i = 0; i < 4; ++i){ c0s[i] = 0.f; c1s[i] = 0.f; }

  const int r88 = (hh * 16 + l15) * 88;
  const int r72 = (hh * 16 + l15) * 72;
  const int stElem = ss * 88 + 64 + cc;          // in(t+1) store offset in cA

  __syncthreads();

  for (int t = 0; t < T_STEPS; ++t){
    short* pA = &H0[(t + 1) & 1][0][0];   // h0(t-1) | in(t)
    short* cA = &H0[t & 1][0][0];         // h0(t)   | in(t+1)

    // ================= layer 0 =================
    floatx4 a0 = { bi0[0], bi0[0], bi0[0], bi0[0] };
    floatx4 a1 = { bi0[1], bi0[1], bi0[1], bi0[1] };
    floatx4 a2 = { bi0[2], bi0[2], bi0[2], bi0[2] };
    floatx4 a3 = { bi0[3], bi0[3], bi0[3], bi0[3] };
    #pragma unroll
    for (int kf = 0; kf < 2; ++kf){
      short8 af = *(const short8*)&pA[r88 + kf * 32 + koff];
      a0 = __builtin_amdgcn_mfma_f32_16x16x32_bf16(af, bf0[0][kf], a0, 0, 0, 0);
      a1 = __builtin_amdgcn_mfma_f32_16x16x32_bf16(af, bf0[1][kf], a1, 0, 0, 0);
      a2 = __builtin_amdgcn_mfma_f32_16x16x32_bf16(af, bf0[2][kf], a2, 0, 0, 0);
      a3 = __builtin_amdgcn_mfma_f32_16x16x32_bf16(af, bf0[3][kf], a3, 0, 0, 0);
    }
    {
      short8 afin = { 0,0,0,0,0,0,0,0 };
      if (quad == 0) afin = *(const short8*)&pA[r88 + 64];
      a0 = __builtin_amdgcn_mfma_f32_16x16x32_bf16(afin, bf0[0][2], a0, 0, 0, 0);
      a1 = __builtin_amdgcn_mfma_f32_16x16x32_bf16(afin, bf0[1][2], a1, 0, 0, 0);
      a2 = __builtin_amdgcn_mfma_f32_16x16x32_bf16(afin, bf0[2][2], a2, 0, 0, 0);
      a3 = __builtin_amdgcn_mfma_f32_16x16x32_bf16(afin, bf0[3][2], a3, 0, 0, 0);
    }
    #pragma unroll
    for (int q = 0; q < 4; ++q){
      float h = lstm_elem(a0[q], a1[q], a2[q], a3[q], c0s[q]);
      cA[(hh * 16 + quad * 4 + q) * 88 + jcol] = (short)f2bf_fast(h);  // h0(t)
    }
    if (act) cA[stElem] = (short)f2bf_fast(rIn);   // in(t+1)
    rIn = loadSlab(t + 2);
    __syncthreads();   // B2: h0(t) + in(t+1) visible

    // ================= layer 1 (K = h0(t) | h1(t-1)) =================
    a0 = floatx4{ bi1[0], bi1[0], bi1[0], bi1[0] };
    a1 = floatx4{ bi1[1], bi1[1], bi1[1], bi1[1] };
    a2 = floatx4{ bi1[2], bi1[2], bi1[2], bi1[2] };
    a3 = floatx4{ bi1[3], bi1[3], bi1[3], bi1[3] };
    #pragma unroll
    for (int kf = 0; kf < 4; ++kf){
      short8 af = (kf < 2) ? *(const short8*)&cA[r88 + kf * 32 + koff]
                           : *(const short8*)&H1[0][r72 + (kf - 2) * 32 + koff];
      const int fbase = (sub * 16 + kf) * 64 * 8 + lane * 8;
      a0 = __builtin_amdgcn_mfma_f32_16x16x32_bf16(af, *(const short8*)&W1s[fbase        ], a0, 0, 0, 0);
      a1 = __builtin_amdgcn_mfma_f32_16x16x32_bf16(af, *(const short8*)&W1s[fbase + 4*512], a1, 0, 0, 0);
      a2 = __builtin_amdgcn_mfma_f32_16x16x32_bf16(af, *(const short8*)&W1s[fbase + 8*512], a2, 0, 0, 0);
      a3 = __builtin_amdgcn_mfma_f32_16x16x32_bf16(af, *(const short8*)&W1s[fbase +12*512], a3, 0, 0, 0);
      // Pin: stop the scheduler hoisting the next kf's 4 ds_read_b128s over
      // these MFMAs (R5: ~80 VGPRs of hoisted staging -> scratch spills).
      __builtin_amdgcn_sched_barrier(0);
    }
    float hn[4];
    #pragma unroll
    for (int q = 0; q < 4; ++q)
      hn[q] = lstm_elem(a0[q], a1[q], a2[q], a3[q], c1s[q]);
    __syncthreads();   // B3: all layer-1 reads of h1(t-1) done
    #pragma unroll
    for (int q = 0; q < 4; ++q)
      H1[hh * 16 + quad * 4 + q][jcol] = (short)f2bf_fast(hn[q]);

    // ================= head (last 48 steps only) =================
    if (t >= 335){
      __syncthreads();   // h1(t) visible
      const int hs = tid >> 4, outc = (tid >> 3) & 1, part = tid & 7;
      const int idx0 = outc * 64 + part * 8;
      short8 hv = *(const short8*)&H1[hs][part * 8];
      floatx4 wa = *(const floatx4*)&H1[idx0 >> 2][64];
      floatx4 wb = *(const floatx4*)&H1[(idx0 >> 2) + 1][64];
      float p = 0.f;
      #pragma unroll
      for (int jj = 0; jj < 4; ++jj){
        p += fmaxf(bf2f((unsigned short)hv[jj]), 0.f) * wa[jj];
        p += fmaxf(bf2f((unsigned short)hv[jj + 4]), 0.f) * wb[jj];
      }
      p += __shfl_xor(p, 1);
      p += __shfl_xor(p, 2);
      p += __shfl_xor(p, 4);
      if (part == 0){
        float val;
        if (outc == 0) val = p + hb0;
        else {
          float x = p + hb1;   // softplus, stable
          val = fmaxf(x, 0.f) + __logf(1.f + __expf(-fabsf(x)));
        }
        outp[(((size_t)b * 48 + (t - 335)) * 512 + (n0 + hs)) * 2 + outc] = val;
      }
    }
  }
}

extern "C" void kernel_launch(void* const* d_in, const int* in_sizes, int n_in,
                              void* d_out, int out_size, void* d_ws, size_t ws_size,
                              hipStream_t stream) {
  (void)in_sizes; (void)n_in; (void)out_size; (void)d_ws; (void)ws_size;
  deepar_kernel<<<dim3(512), dim3(512), 0, stream>>>(
      (const float*)d_in[0],  (const float*)d_in[1],
      (const float*)d_in[2],  (const float*)d_in[3],
      (const float*)d_in[4],  (const float*)d_in[5],
      (const float*)d_in[6],  (const float*)d_in[7],
      (const float*)d_in[8],  (const float*)d_in[9],
      (const float*)d_in[10], (const float*)d_in[11],
      (const float*)d_in[12], (const float*)d_in[13],
      (float*)d_out);
}

// Round 7
// 1436.736 us; speedup vs baseline: 1.2331x; 1.0232x over previous
//
#include <hip/hip_runtime.h>

// DeepAR forward: B=32, L_IN=336, L_OUT=48, N=512, COV=4, EMB=32, H=64
// T = 383 steps, 16384 independent sequences.
// R7 = R3's no-spill shell (512 WGs x 256 thr, 32 seqs/WG, bf0 in regs,
// W1 in LDS, merged A buffer stride 168, 2 waves/SIMD) with the elementwise
// math cut from 10 -> 5 transcendentals/element (trans ~16 cyc issue each =
// the measured bottleneck): sigmoids via exp2 on -log2e-prescaled gates,
// tanh via Pade(7,6) rational, divisions merged to 2 rcp/element.

#define T_STEPS 383
#define AST 168   // A row stride in shorts: [h0 0..63 | h1 64..127 | in 128..132 | pad]
#define LOG2E 1.4426950408889634f

typedef __attribute__((ext_vector_type(8))) short short8;
typedef __attribute__((ext_vector_type(4))) float floatx4;

static __device__ __forceinline__ unsigned short f2bf(float f){   // RNE
  union { float f; unsigned u; } v; v.f = f;
  unsigned u = v.u + 0x7fffu + ((v.u >> 16) & 1u);
  return (unsigned short)(u >> 16);
}
static __device__ __forceinline__ unsigned short f2bf_fast(float f){  // round-half-up
  union { float f; unsigned u; } v; v.f = f;
  return (unsigned short)((v.u + 0x8000u) >> 16);
}
static __device__ __forceinline__ float bf2f(unsigned short b){
  union { unsigned u; float f; } v; v.u = ((unsigned)b) << 16; return v.f;
}

// iv, fv, ov pre-scaled by -log2e (so exp2 gives e^-gate); gv raw.
// tanh via Pade(7,6) clamped at +-4.97 (err <= 1.4e-4, validated R4).
// 3 exp2 + 2 rcp + ~30 VALU.
static __device__ __forceinline__ float lstm_elem(float iv, float fv,
                                                  float gv, float ov,
                                                  float& c){
  float Ei = __builtin_amdgcn_exp2f(fminf(iv, 40.f));
  float Ef = __builtin_amdgcn_exp2f(fminf(fv, 40.f));
  float Eo = __builtin_amdgcn_exp2f(fminf(ov, 40.f));
  float gc = fmaxf(-4.97f, fminf(4.97f, gv));
  float g2 = gc * gc;
  float pg = gc * fmaf(g2, fmaf(g2, g2 + 378.f, 17325.f), 135135.f);
  float qg = fmaf(g2, fmaf(g2, fmaf(g2, 28.f, 3150.f), 62370.f), 135135.f);
  float fi = 1.f + Ei, ff = 1.f + Ef;
  float t2 = qg * fi;                     // qg (1+Ei)
  float num = fmaf(c, t2, pg * ff);       // c qg (1+Ei) + pg (1+Ef)
  c = num * __builtin_amdgcn_rcpf(t2 * ff);
  float cc = fmaxf(-4.97f, fminf(4.97f, c));
  float c2 = cc * cc;
  float pc = cc * fmaf(c2, fmaf(c2, c2 + 378.f, 17325.f), 135135.f);
  float qc = fmaf(c2, fmaf(c2, fmaf(c2, 28.f, 3150.f), 62370.f), 135135.f);
  return pc * __builtin_amdgcn_rcpf(qc * (1.f + Eo));   // sig(o) tanh(c)
}

__global__ __launch_bounds__(256, 2) void deepar_kernel(
    const float* __restrict__ hist, const float* __restrict__ fut,
    const float* __restrict__ embW, const float* __restrict__ embB,
    const float* __restrict__ Wih0, const float* __restrict__ Whh0,
    const float* __restrict__ bih0, const float* __restrict__ bhh0,
    const float* __restrict__ Wih1, const float* __restrict__ Whh1,
    const float* __restrict__ bih1, const float* __restrict__ bhh1,
    const float* __restrict__ headW, const float* __restrict__ headB,
    float* __restrict__ outp)
{
  const int tid  = threadIdx.x;
  const int lane = tid & 63;
  const int wv   = tid >> 6;        // wave -> gate-column sub-block
  const int l15  = lane & 15;
  const int quad = lane >> 4;       // 0..3
  const int koff = quad * 8;
  const int jcol = wv * 16 + l15;   // hidden-unit index this lane owns

  const int b  = blockIdx.x >> 4;            // batch
  const int n0 = (blockIdx.x & 15) * 32;     // first series index

  __shared__ __align__(16) unsigned short A[32 * AST];
  __shared__ __align__(16) unsigned short W1[256 * 128];  // layer-1 B-frags, frag-ordered
  __shared__ float HW[128];

  for (int i = tid; i < 32 * AST; i += 256) A[i] = 0;
  if (tid < 128) HW[tid] = headW[tid];
  const float hb0 = headB[0], hb1 = headB[1];

  // ---- layer-0 weight B-fragments in registers; layer-1 frags -> LDS ----
  // B-frag (16x16x32): lane holds B^T[n=lane&15][k = quad*8 + j], j=0..7
  // Per-gate prescale: i,f,o rows * -log2e (for exp2 sigmoids); g rows raw
  // (Pade tanh consumes the raw gate).
  short8 bf0[4][3];   // [gate][kf]: kf0,1 = Whh0 (k 0..63); kf2 = input cols
  float  bi0[4], bi1[4];
  #pragma unroll
  for (int g = 0; g < 4; ++g){
    const float scale = (g == 2) ? 1.0f : -LOG2E;
    const int r = g * 64 + wv * 16 + l15;     // gate row 0..255
    float u = 0.f, bb = bih0[r] + bhh0[r];
    #pragma unroll
    for (int e = 0; e < 32; ++e){
      float wval = Wih0[r * 36 + e];
      u  += wval * embW[e];
      bb += wval * embB[e];
    }
    bi0[g] = bb * scale;
    bi1[g] = (bih1[r] + bhh1[r]) * scale;
    #pragma unroll
    for (int kf = 0; kf < 2; ++kf)
      #pragma unroll
      for (int j = 0; j < 8; ++j)
        bf0[g][kf][j] = (short)f2bf(Whh0[r * 64 + kf * 32 + koff + j] * scale);
    #pragma unroll
    for (int j = 0; j < 8; ++j){
      int kk = koff + j;          // local k within input frag; col = 128+kk
      float v = 0.f;
      if (kk == 0) v = u;                               // prev -> u[r]
      else if (kk >= 1 && kk <= 4) v = Wih0[r * 36 + 32 + (kk - 1)];
      bf0[g][2][j] = (short)f2bf(v * scale);
    }
    #pragma unroll
    for (int kf = 0; kf < 4; ++kf){
      const float* src = (kf < 2) ? (Wih1 + r * 64 + kf * 32)
                                  : (Whh1 + r * 64 + (kf - 2) * 32);
      short8 w;
      #pragma unroll
      for (int j = 0; j < 8; ++j)
        w[j] = (short)f2bf(src[koff + j] * scale);
      // frag-ordered: wave wv's (g,kf) frag at contiguous 64x16B, lane-linear
      *(short8*)&W1[(((wv * 16 + g * 4 + kf) * 64) + lane) * 8] = w;
    }
  }

  // ---- input staging (prev: 32 threads; cov: 128 threads) ----
  const bool isPrev = (tid < 32);
  const bool isCov  = (tid >= 64 && tid < 192);
  int ss = 0, cc = 0;
  if (isPrev){ ss = tid; cc = 0; }
  if (isCov) { ss = (tid - 64) >> 2; cc = 1 + ((tid - 64) & 3); }
  const int myN = n0 + ss;

  auto loadSlab = [&](int tt) -> float {
    if (isPrev){
      int l = tt; if (l > 383) l = 383;
      return (l < 336) ? hist[(((size_t)b * 336 + l) * 512 + myN) * 5]
                       : fut [(((size_t)b * 48 + (l - 336)) * 512 + myN) * 5];
    } else if (isCov){
      int l = tt + 1; if (l > 383) l = 383;
      return (l < 336) ? hist[(((size_t)b * 336 + l) * 512 + myN) * 5 + cc]
                       : fut [(((size_t)b * 48 + (l - 336)) * 512 + myN) * 5 + cc];
    }
    return 0.f;
  };

  float rIn = loadSlab(0);
  if (isPrev || isCov) A[ss * AST + 128 + cc] = f2bf(rIn);
  rIn = loadSlab(1);   // prefetch step 1

  float c0s[8], c1s[8];
  #pragma unroll
  for (int i = 0; i < 8; ++i){ c0s[i] = 0.f; c1s[i] = 0.f; }

  __syncthreads();

  for (int t = 0; t < T_STEPS; ++t){
    // ================= layer 0 (K-frags at col 0,32,128) =================
    floatx4 acc[4][2];
    #pragma unroll
    for (int g = 0; g < 4; ++g)
      #pragma unroll
      for (int mt = 0; mt < 2; ++mt){
        floatx4 binit = { bi0[g], bi0[g], bi0[g], bi0[g] };
        acc[g][mt] = binit;
      }
    const int c0off[3] = { 0, 32, 128 };
    #pragma unroll
    for (int mt = 0; mt < 2; ++mt){
      #pragma unroll
      for (int kf = 0; kf < 3; ++kf){
        short8 af = *(const short8*)&A[(mt * 16 + l15) * AST + c0off[kf] + koff];
        #pragma unroll
        for (int g = 0; g < 4; ++g)
          acc[g][mt] = __builtin_amdgcn_mfma_f32_16x16x32_bf16(af, bf0[g][kf], acc[g][mt], 0, 0, 0);
      }
    }
    float hn[8];
    #pragma unroll
    for (int mt = 0; mt < 2; ++mt)
      #pragma unroll
      for (int q = 0; q < 4; ++q){
        int idx = mt * 4 + q;
        hn[idx] = lstm_elem(acc[0][mt][q], acc[1][mt][q],
                            acc[2][mt][q], acc[3][mt][q], c0s[idx]);
      }
    __syncthreads();   // B1: all layer-0 reads of A done
    #pragma unroll
    for (int mt = 0; mt < 2; ++mt)
      #pragma unroll
      for (int q = 0; q < 4; ++q){
        int s = mt * 16 + quad * 4 + q;
        A[s * AST + jcol] = f2bf_fast(hn[mt * 4 + q]);   // h0(t)
      }
    if (isPrev || isCov) A[ss * AST + 128 + cc] = f2bf_fast(rIn);  // inputs t+1
    rIn = loadSlab(t + 2);                                          // prefetch t+2
    __syncthreads();   // B2: h0 + inputs visible

    // ================= layer 1 (K = h0|h1, cols 0..127; W from LDS) ======
    #pragma unroll
    for (int g = 0; g < 4; ++g)
      #pragma unroll
      for (int mt = 0; mt < 2; ++mt){
        floatx4 binit = { bi1[g], bi1[g], bi1[g], bi1[g] };
        acc[g][mt] = binit;
      }
    #pragma unroll
    for (int kf = 0; kf < 4; ++kf){
      short8 wfr[4];
      #pragma unroll
      for (int g = 0; g < 4; ++g)
        wfr[g] = *(const short8*)&W1[(((wv * 16 + g * 4 + kf) * 64) + lane) * 8];
      #pragma unroll
      for (int mt = 0; mt < 2; ++mt){
        short8 af = *(const short8*)&A[(mt * 16 + l15) * AST + kf * 32 + koff];
        #pragma unroll
        for (int g = 0; g < 4; ++g)
          acc[g][mt] = __builtin_amdgcn_mfma_f32_16x16x32_bf16(af, wfr[g], acc[g][mt], 0, 0, 0);
      }
    }
    #pragma unroll
    for (int mt = 0; mt < 2; ++mt)
      #pragma unroll
      for (int q = 0; q < 4; ++q){
        int idx = mt * 4 + q;
        hn[idx] = lstm_elem(acc[0][mt][q], acc[1][mt][q],
                            acc[2][mt][q], acc[3][mt][q], c1s[idx]);
      }
    __syncthreads();   // B3: all layer-1 reads of h1(t-1) done
    #pragma unroll
    for (int mt = 0; mt < 2; ++mt)
      #pragma unroll
      for (int q = 0; q < 4; ++q){
        int s = mt * 16 + quad * 4 + q;
        A[s * AST + 64 + jcol] = f2bf_fast(hn[mt * 4 + q]);   // h1(t)
      }
    // next step's layer-0 reads only cols 0..63/128.. — head syncs itself.

    // ================= head (only last 48 steps produce output) =========
    if (t >= 335){
      __syncthreads();   // h1 visible for head reads
      const int hs = tid >> 3, outc = (tid >> 2) & 1, part = tid & 3;
      const short8 hv0 = *(const short8*)&A[hs * AST + 64 + part * 16];
      const short8 hv1 = *(const short8*)&A[hs * AST + 64 + part * 16 + 8];
      float p = 0.f;
      #pragma unroll
      for (int jj = 0; jj < 8; ++jj){
        float a0 = fmaxf(bf2f((unsigned short)hv0[jj]), 0.f);
        float a1 = fmaxf(bf2f((unsigned short)hv1[jj]), 0.f);
        p += a0 * HW[outc * 64 + part * 16 + jj];
        p += a1 * HW[outc * 64 + part * 16 + 8 + jj];
      }
      p += __shfl_xor(p, 1);
      p += __shfl_xor(p, 2);
      if ((tid & 3) == 0){
        float val;
        if (outc == 0) val = p + hb0;
        else {
          float x = p + hb1;   // softplus, stable
          val = fmaxf(x, 0.f) + __logf(1.f + __expf(-fabsf(x)));
        }
        outp[(((size_t)b * 48 + (t - 335)) * 512 + (n0 + hs)) * 2 + outc] = val;
      }
    }
  }
}

extern "C" void kernel_launch(void* const* d_in, const int* in_sizes, int n_in,
                              void* d_out, int out_size, void* d_ws, size_t ws_size,
                              hipStream_t stream) {
  (void)in_sizes; (void)n_in; (void)out_size; (void)d_ws; (void)ws_size;
  deepar_kernel<<<dim3(512), dim3(256), 0, stream>>>(
      (const float*)d_in[0],  (const float*)d_in[1],
      (const float*)d_in[2],  (const float*)d_in[3],
      (const float*)d_in[4],  (const float*)d_in[5],
      (const float*)d_in[6],  (const float*)d_in[7],
      (const float*)d_in[8],  (const float*)d_in[9],
      (const float*)d_in[10], (const float*)d_in[11],
      (const float*)d_in[12], (const float*)d_in[13],
      (float*)d_out);
}